// Round 1
// baseline (224.824 us; speedup 1.0000x reference)
//
#include <hip/hip_runtime.h>
#include <hip/hip_bf16.h>

// Problem constants
#define B_   16
#define C_   256
#define T_   2048
#define PS   12
#define NNEG 15
#define OFFS 16
#define COPIES 16

// Derived
#define M_GEMM (B_ * T_)        // 32768 rows (b,t)
#define N_GEMM (C_ * PS)        // 3072 cols (j = i*256 + o)
#define K_GEMM C_               // 256
#define NPRED 6225408           // sum_i (2032-i)*256
#define NLAB  389088

using bf16 = __hip_bfloat16;
typedef __attribute__((ext_vector_type(4))) float f32x4;
typedef __attribute__((ext_vector_type(8))) short bf16x8;

// ---------------------------------------------------------------- transpose z
// z[b][c][t] f32  ->  zT[b][t][c] bf16
__global__ __launch_bounds__(256) void transpose_z(const float* __restrict__ z,
                                                   bf16* __restrict__ zT) {
    __shared__ float tile[32][33];
    int t0 = blockIdx.x * 32, c0 = blockIdx.y * 32, b = blockIdx.z;
    int col = threadIdx.x & 31, r = threadIdx.x >> 5;  // 8 rows per pass
    for (int rr = 0; rr < 4; ++rr) {
        int row = r + rr * 8;  // c-dim
        tile[row][col] = z[(size_t)(b * C_ + c0 + row) * T_ + t0 + col];
    }
    __syncthreads();
    for (int rr = 0; rr < 4; ++rr) {
        int row = r + rr * 8;  // t-dim
        zT[(size_t)(b * T_ + t0 + row) * C_ + c0 + col] =
            __float2bfloat16(tile[col][row]);
    }
}

// ---------------------------------------------------------------- pack weight
// w[c][o][i] f32 -> wTb[j][c] bf16 with j = i*256 + o
__global__ __launch_bounds__(256) void pack_w(const float* __restrict__ w,
                                              bf16* __restrict__ wTb) {
    int gid = blockIdx.x * 256 + threadIdx.x;  // 3072*256 total
    int j = gid >> 8, c = gid & 255;
    int o = j & 255, i = j >> 8;
    wTb[gid] = __float2bfloat16(w[(size_t)c * (C_ * PS) + o * PS + i]);
}

// ---------------------------------------------------------------- z_pred GEMM
// zT[M][256] bf16 x wTb[N][256] bf16 -> zp_diag staggered bf16
// zp_diag[b][s][i][o] = z_pred[b,o,s-16-i,i] + bias[o],  s = t+16+i < T
#define BM 128
#define BN 128
#define BK 32

__global__ __launch_bounds__(256) void gemm_zpred(const bf16* __restrict__ zT,
                                                  const bf16* __restrict__ wTb,
                                                  const float* __restrict__ bias,
                                                  bf16* __restrict__ zp) {
    __shared__ bf16 lA[BM * BK];  // 8KB [128][32]
    __shared__ bf16 lB[BN * BK];  // 8KB
    int bid = blockIdx.x;
    int bn = bid % (N_GEMM / BN);   // 24
    int bm = bid / (N_GEMM / BN);   // 256
    int tid = threadIdx.x;
    int wid = tid >> 6, lane = tid & 63;
    int ln15 = lane & 15, kg = lane >> 4;
    int wm = (wid & 1) * 64, wn = (wid >> 1) * 64;
    int row0 = bm * BM, col0 = bn * BN;

    f32x4 acc[4][4] = {};

    const bf16* gA = zT + (size_t)(row0 + (tid >> 2)) * 256 + (tid & 3) * 8;
    const bf16* gB = wTb + (size_t)(col0 + (tid >> 2)) * 256 + (tid & 3) * 8;
    char* lAw = (char*)lA + wid * 1024;  // wave-uniform LDS base (+ lane*16)
    char* lBw = (char*)lB + wid * 1024;

    for (int kt = 0; kt < K_GEMM / BK; ++kt) {
        if (kt) __syncthreads();
        const bf16* ga = gA + kt * BK;
        const bf16* gb = gB + kt * BK;
        __builtin_amdgcn_global_load_lds(
            (const __attribute__((address_space(1))) void*)ga,
            (__attribute__((address_space(3))) void*)lAw, 16, 0, 0);
        __builtin_amdgcn_global_load_lds(
            (const __attribute__((address_space(1))) void*)(ga + 64 * 256),
            (__attribute__((address_space(3))) void*)(lAw + 4096), 16, 0, 0);
        __builtin_amdgcn_global_load_lds(
            (const __attribute__((address_space(1))) void*)gb,
            (__attribute__((address_space(3))) void*)lBw, 16, 0, 0);
        __builtin_amdgcn_global_load_lds(
            (const __attribute__((address_space(1))) void*)(gb + 64 * 256),
            (__attribute__((address_space(3))) void*)(lBw + 4096), 16, 0, 0);
        __syncthreads();

        bf16x8 af[4], bf[4];
#pragma unroll
        for (int mi = 0; mi < 4; ++mi)
            af[mi] = *(const bf16x8*)&lA[(wm + mi * 16 + ln15) * BK + kg * 8];
#pragma unroll
        for (int ni = 0; ni < 4; ++ni)
            bf[ni] = *(const bf16x8*)&lB[(wn + ni * 16 + ln15) * BK + kg * 8];
#pragma unroll
        for (int mi = 0; mi < 4; ++mi)
#pragma unroll
            for (int ni = 0; ni < 4; ++ni)
                acc[mi][ni] = __builtin_amdgcn_mfma_f32_16x16x32_bf16(
                    af[mi], bf[ni], acc[mi][ni], 0, 0, 0);
    }

    // epilogue: staggered store, D col = lane&15 (o), D row = kg*4+r ((b,t))
#pragma unroll
    for (int ni = 0; ni < 4; ++ni) {
        int j = col0 + wn + ni * 16;
        int istep = j >> 8;               // prediction step i
        int o = (j & 255) + ln15;         // output channel
        float bv = bias[o];
#pragma unroll
        for (int mi = 0; mi < 4; ++mi) {
            int rowb = row0 + wm + mi * 16 + kg * 4;
#pragma unroll
            for (int r = 0; r < 4; ++r) {
                int row = rowb + r;
                int b = row >> 11, t = row & (T_ - 1);
                int s = t + OFFS + istep;
                if (s < T_)
                    zp[((size_t)(b * T_ + s) * PS + istep) * 256 + o] =
                        __float2bfloat16(acc[mi][ni][r] + bv);
            }
        }
    }
}

// ---------------------------------------------------------------- predictions
// one wave per (b, s): D[n][i] = sum_c targets[n][c] * zp_diag[b][s][i][c]
__global__ __launch_bounds__(256) void predict_kernel(
    const bf16* __restrict__ zT, const bf16* __restrict__ zp,
    const int* __restrict__ neg, float* __restrict__ out) {
    int tid = threadIdx.x;
    int wid = tid >> 6, lane = tid & 63;
    int ln15 = lane & 15, kg = lane >> 4;
    int gw = blockIdx.x * 4 + wid;         // 0 .. 16*2032-1
    int b = gw / (T_ - OFFS);
    int s = OFFS + gw % (T_ - OFFS);

    // A row source (target n = ln15): row index into zT's 32768 rows
    int src;
    if (ln15 == 0) src = b * T_ + s;
    else           src = neg[b * (NNEG * T_) + (ln15 - 1) * T_ + s];
    const bf16* arow = zT + (size_t)src * 256 + kg * 8;
    // B col (step i = ln15) from staggered zp (i=12..15 reads padded garbage,
    // harmless: MFMA columns are independent and those cols are not stored)
    const bf16* brow = zp + ((size_t)(b * T_ + s) * PS + ln15) * 256 + kg * 8;

    f32x4 acc = {0.f, 0.f, 0.f, 0.f};
#pragma unroll
    for (int kk = 0; kk < 8; ++kk) {
        bf16x8 a = *(const bf16x8*)(arow + kk * 32);
        bf16x8 bb = *(const bf16x8*)(brow + kk * 32);
        acc = __builtin_amdgcn_mfma_f32_16x16x32_bf16(a, bb, acc, 0, 0, 0);
    }

    // D col = ln15 = step i ; D rows = kg*4 + r = target copy n
    int i = ln15;
    int imax = s - OFFS; if (imax > PS - 1) imax = PS - 1;
    if (i <= imax) {
        int t = s - OFFS - i;
        int base_i = 256 * ((T_ - OFFS) * i - (i * (i - 1)) / 2);
        float* o = out + base_i + (t * B_ + b) * COPIES + kg * 4;
        o[0] = acc[0]; o[1] = acc[1]; o[2] = acc[2]; o[3] = acc[3];
    }
}

// ---------------------------------------------------------------- launch
extern "C" void kernel_launch(void* const* d_in, const int* in_sizes, int n_in,
                              void* d_out, int out_size, void* d_ws, size_t ws_size,
                              hipStream_t stream) {
    const float* z    = (const float*)d_in[0];
    const float* w    = (const float*)d_in[1];
    const float* bias = (const float*)d_in[2];
    const int*   neg  = (const int*)d_in[3];
    float* out = (float*)d_out;

    // workspace layout
    char* ws = (char*)d_ws;
    const size_t ZP_BYTES = (size_t)B_ * T_ * PS * 256 * sizeof(bf16); // 201326592
    bf16* zp  = (bf16*)ws;                                   // + 8KB pad for i=12..15 overread
    bf16* zT  = (bf16*)(ws + ZP_BYTES + 8192);               // 16777216 B
    bf16* wTb = (bf16*)(ws + ZP_BYTES + 8192 + (size_t)M_GEMM * 256 * sizeof(bf16));

    transpose_z<<<dim3(T_ / 32, C_ / 32, B_), 256, 0, stream>>>(z, zT);
    pack_w<<<(N_GEMM * 256) / 256, 256, 0, stream>>>(w, wTb);
    gemm_zpred<<<(M_GEMM / BM) * (N_GEMM / BN), 256, 0, stream>>>(zT, wTb, bias, zp);
    predict_kernel<<<(B_ * (T_ - OFFS)) / 4, 256, 0, stream>>>(zT, zp, neg, out);
    hipMemsetAsync(out + NPRED, 0, NLAB * sizeof(float), stream);
}

// Round 2
// 166.362 us; speedup vs baseline: 1.3514x; 1.3514x over previous
//
#include <hip/hip_runtime.h>
#include <hip/hip_bf16.h>

// Problem constants
#define B_   16
#define C_   256
#define T_   2048
#define PS   12
#define NNEG 15
#define OFFS 16
#define COPIES 16

// Derived
#define M_GEMM (B_ * T_)        // 32768 rows (b,t)
#define N_GEMM (C_ * PS)        // 3072 cols (j = i*256 + o)
#define K_GEMM C_               // 256
#define NPRED 6225408           // sum_i (2032-i)*256
#define NLAB  389088

using bf16 = __hip_bfloat16;
typedef __attribute__((ext_vector_type(4))) float f32x4;
typedef __attribute__((ext_vector_type(8))) short bf16x8;

// ---------------------------------------------------------------- transpose z
// z[b][c][t] f32  ->  zT[b][t][c] bf16
__global__ __launch_bounds__(256) void transpose_z(const float* __restrict__ z,
                                                   bf16* __restrict__ zT) {
    __shared__ float tile[32][33];
    int t0 = blockIdx.x * 32, c0 = blockIdx.y * 32, b = blockIdx.z;
    int col = threadIdx.x & 31, r = threadIdx.x >> 5;  // 8 rows per pass
    for (int rr = 0; rr < 4; ++rr) {
        int row = r + rr * 8;  // c-dim
        tile[row][col] = z[(size_t)(b * C_ + c0 + row) * T_ + t0 + col];
    }
    __syncthreads();
    for (int rr = 0; rr < 4; ++rr) {
        int row = r + rr * 8;  // t-dim
        zT[(size_t)(b * T_ + t0 + row) * C_ + c0 + col] =
            __float2bfloat16(tile[col][row]);
    }
}

// ---------------------------------------------------------------- pack weight
// w[c][o][i] f32 -> wTb[j][c] bf16 with j = i*256 + o
__global__ __launch_bounds__(256) void pack_w(const float* __restrict__ w,
                                              bf16* __restrict__ wTb) {
    int gid = blockIdx.x * 256 + threadIdx.x;  // 3072*256 total
    int j = gid >> 8, c = gid & 255;
    int o = j & 255, i = j >> 8;
    wTb[gid] = __float2bfloat16(w[(size_t)c * (C_ * PS) + o * PS + i]);
}

// ---------------------------------------------------------------- z_pred GEMM
// zT[M][256] bf16 x wTb[N][256] bf16 -> zp_diag staggered bf16
// zp_diag[b][s][i][o] = z_pred[b,o,s-16-i,i] + bias[o],  s = t+16+i < T
// BK=64, XOR-swizzled LDS staging (16B granule ^= row&7), LDS-staged epilogue.
#define BM 128
#define BN 128
#define BK 64
#define EPAD 136   // epilogue row stride in bf16 (272 B, 16B-aligned, banks +4/row)

__global__ __launch_bounds__(256) void gemm_zpred(const bf16* __restrict__ zT,
                                                  const bf16* __restrict__ wTb,
                                                  const float* __restrict__ bias,
                                                  bf16* __restrict__ zp) {
    // union: staging (A 16KB + B 16KB) vs epilogue tile (128*136*2 = 34816 B)
    __shared__ __align__(16) char smem[BM * EPAD * 2];
    bf16* lA = (bf16*)smem;              // [128][64] swizzled
    bf16* lB = (bf16*)(smem + 16384);    // [128][64] swizzled
    bf16* lE = (bf16*)smem;              // [128][EPAD]

    // bijective XCD swizzle: grid = 6144 = 8 * 768
    int bid = (blockIdx.x & 7) * 768 + (blockIdx.x >> 3);
    int bn = bid % (N_GEMM / BN);   // 24
    int bm = bid / (N_GEMM / BN);   // 256
    int tid = threadIdx.x;
    int wid = tid >> 6, lane = tid & 63;
    int ln15 = lane & 15, kg = lane >> 4;
    int wm = (wid & 1) * 64, wn = (wid >> 1) * 64;
    int row0 = bm * BM, col0 = bn * BN;
    int i_step = col0 >> 8;         // single prediction step per block
    int o0 = col0 & 255;            // channel offset (0 or 128)

    f32x4 acc[4][4] = {};

    // staging addresses: LDS slot (row, g) holds global granule g ^ (row&7).
    // row = it*32 + wid*8 + (lane>>3)  ->  row&7 == (lane>>3)&7
    int rsw = (((lane & 7) ^ ((lane >> 3) & 7)) * 8);  // element col within 64
    int srow = wid * 8 + (lane >> 3);                  // 0..31 per it
    const bf16* gA0 = zT + (size_t)(row0 + srow) * 256 + rsw;
    const bf16* gB0 = wTb + (size_t)(col0 + srow) * 256 + rsw;

#pragma unroll
    for (int kt = 0; kt < K_GEMM / BK; ++kt) {
        if (kt) __syncthreads();
#pragma unroll
        for (int it = 0; it < 4; ++it) {
            __builtin_amdgcn_global_load_lds(
                (const __attribute__((address_space(1))) void*)(gA0 + it * (size_t)(32 * 256) + kt * BK),
                (__attribute__((address_space(3))) void*)(smem + it * 4096 + wid * 1024), 16, 0, 0);
            __builtin_amdgcn_global_load_lds(
                (const __attribute__((address_space(1))) void*)(gB0 + it * (size_t)(32 * 256) + kt * BK),
                (__attribute__((address_space(3))) void*)(smem + 16384 + it * 4096 + wid * 1024), 16, 0, 0);
        }
        __syncthreads();

#pragma unroll
        for (int kk = 0; kk < 2; ++kk) {
            bf16x8 af[4], bfr[4];
#pragma unroll
            for (int mi = 0; mi < 4; ++mi) {
                int row = wm + mi * 16 + ln15;
                int g = (kk * 4 + kg) ^ (ln15 & 7);
                af[mi] = *(const bf16x8*)&lA[row * BK + g * 8];
            }
#pragma unroll
            for (int ni = 0; ni < 4; ++ni) {
                int row = wn + ni * 16 + ln15;
                int g = (kk * 4 + kg) ^ (ln15 & 7);
                bfr[ni] = *(const bf16x8*)&lB[row * BK + g * 8];
            }
#pragma unroll
            for (int mi = 0; mi < 4; ++mi)
#pragma unroll
                for (int ni = 0; ni < 4; ++ni)
                    acc[mi][ni] = __builtin_amdgcn_mfma_f32_16x16x32_bf16(
                        af[mi], bfr[ni], acc[mi][ni], 0, 0, 0);
        }
    }

    // ---------------- epilogue: acc -> LDS (bf16, +bias) -> coalesced stores
    __syncthreads();  // all waves done reading staging LDS

    float bv[4];
#pragma unroll
    for (int ni = 0; ni < 4; ++ni) bv[ni] = bias[o0 + wn + ni * 16 + ln15];

#pragma unroll
    for (int mi = 0; mi < 4; ++mi)
#pragma unroll
        for (int ni = 0; ni < 4; ++ni) {
            int col_e = wn + ni * 16 + ln15;
#pragma unroll
            for (int r = 0; r < 4; ++r) {
                int row_e = wm + mi * 16 + kg * 4 + r;
                lE[row_e * EPAD + col_e] = __float2bfloat16(acc[mi][ni][r] + bv[ni]);
            }
        }

    __syncthreads();

#pragma unroll
    for (int e = 0; e < 8; ++e) {
        int row_e = e * 16 + (tid >> 4);
        int grow = row0 + row_e;
        int b = grow >> 11, t = grow & (T_ - 1);
        int s = t + OFFS + i_step;
        if (s < T_) {
            bf16x8 v = *(const bf16x8*)&lE[row_e * EPAD + (tid & 15) * 8];
            *(bf16x8*)(zp + ((size_t)(b * T_ + s) * PS + i_step) * 256 + o0 +
                       (tid & 15) * 8) = v;
        }
    }
}

// ---------------------------------------------------------------- predictions
// one wave per (b, s): D[n][i] = sum_c targets[n][c] * zp_diag[b][s][i][c]
__global__ __launch_bounds__(256) void predict_kernel(
    const bf16* __restrict__ zT, const bf16* __restrict__ zp,
    const int* __restrict__ neg, float* __restrict__ out) {
    int tid = threadIdx.x;
    int wid = tid >> 6, lane = tid & 63;
    int ln15 = lane & 15, kg = lane >> 4;
    int gw = blockIdx.x * 4 + wid;         // 0 .. 16*2032-1
    int b = gw / (T_ - OFFS);
    int s = OFFS + gw % (T_ - OFFS);

    // A row source (target n = ln15): row index into zT's 32768 rows
    int src;
    if (ln15 == 0) src = b * T_ + s;
    else           src = neg[b * (NNEG * T_) + (ln15 - 1) * T_ + s];
    const bf16* arow = zT + (size_t)src * 256 + kg * 8;
    // B col (step i = ln15) from staggered zp (i=12..15 reads padded garbage,
    // harmless: MFMA columns are independent and those cols are not stored)
    const bf16* brow = zp + ((size_t)(b * T_ + s) * PS + ln15) * 256 + kg * 8;

    f32x4 acc = {0.f, 0.f, 0.f, 0.f};
#pragma unroll
    for (int kk = 0; kk < 8; ++kk) {
        bf16x8 a = *(const bf16x8*)(arow + kk * 32);
        bf16x8 bb = *(const bf16x8*)(brow + kk * 32);
        acc = __builtin_amdgcn_mfma_f32_16x16x32_bf16(a, bb, acc, 0, 0, 0);
    }

    // D col = ln15 = step i ; D rows = kg*4 + r = target copy n
    int i = ln15;
    int imax = s - OFFS; if (imax > PS - 1) imax = PS - 1;
    if (i <= imax) {
        int t = s - OFFS - i;
        int base_i = 256 * ((T_ - OFFS) * i - (i * (i - 1)) / 2);
        float* o = out + base_i + (t * B_ + b) * COPIES + kg * 4;
        o[0] = acc[0]; o[1] = acc[1]; o[2] = acc[2]; o[3] = acc[3];
    }
}

// ---------------------------------------------------------------- launch
extern "C" void kernel_launch(void* const* d_in, const int* in_sizes, int n_in,
                              void* d_out, int out_size, void* d_ws, size_t ws_size,
                              hipStream_t stream) {
    const float* z    = (const float*)d_in[0];
    const float* w    = (const float*)d_in[1];
    const float* bias = (const float*)d_in[2];
    const int*   neg  = (const int*)d_in[3];
    float* out = (float*)d_out;

    // workspace layout
    char* ws = (char*)d_ws;
    const size_t ZP_BYTES = (size_t)B_ * T_ * PS * 256 * sizeof(bf16); // 201326592
    bf16* zp  = (bf16*)ws;                                   // + 8KB pad for i=12..15 overread
    bf16* zT  = (bf16*)(ws + ZP_BYTES + 8192);               // 16777216 B
    bf16* wTb = (bf16*)(ws + ZP_BYTES + 8192 + (size_t)M_GEMM * 256 * sizeof(bf16));

    transpose_z<<<dim3(T_ / 32, C_ / 32, B_), 256, 0, stream>>>(z, zT);
    pack_w<<<(N_GEMM * 256) / 256, 256, 0, stream>>>(w, wTb);
    gemm_zpred<<<(M_GEMM / BM) * (N_GEMM / BN), 256, 0, stream>>>(zT, wTb, bias, zp);
    predict_kernel<<<(B_ * (T_ - OFFS)) / 4, 256, 0, stream>>>(zT, zp, neg, out);
    hipMemsetAsync(out + NPRED, 0, NLAB * sizeof(float), stream);
}